// Round 3
// baseline (435.686 us; speedup 1.0000x reference)
//
#include <hip/hip_runtime.h>
#include <stdint.h>

#define N_ANCH 102400
#define FMP 320
#define NUM_CLASSES 80
#define K_TOP 1000
#define NMS_T 0.6f
#define SC_CLAMP 6.907755278982137f
#define IMGF 1280.0f
#define NBINS 16384   // scores in (0,1) => float bits>>16 < 0x4000

// ---- workspace layout (bytes) ----
#define OFF_SCORES   0u          // f32[102400]
#define OFF_LABELS   409600u     // u32[102400]
#define OFF_HIST     819200u     // u32[16384]
#define OFF_META     884736u     // u32[64]  [0]=cutoff bin, [2]=candidate counter
#define OFF_KEYS     884992u     // u64[4096]
#define OFF_BOXES    917760u     // f32[4000] (16B aligned)
#define OFF_LAB1K    933760u     // u32[1000]
#define OFF_MASK     937760u     // u64[16000]

__device__ __forceinline__ float sigf(float x) {
    return 1.0f / (1.0f + expf(-x));
}

// K0: zero hist (16384) + meta (64) — contiguous
__global__ __launch_bounds__(256) void k_zero(uint32_t* hist) {
    int i = blockIdx.x * 256 + threadIdx.x;
    if (i < NBINS + 64) hist[i] = 0u;
}

// K1: fused score + argmax. 4 threads per anchor, 5 float4 loads per thread.
// NO global atomics here (they serialized on hot bins in R2: 131us).
__global__ __launch_bounds__(256) void k_scores(const float* __restrict__ hmp,
                                                const float* __restrict__ iou,
                                                float* __restrict__ scores,
                                                uint32_t* __restrict__ labels) {
    int gid = blockIdx.x * 256 + threadIdx.x;
    int a = gid >> 2;
    int q = gid & 3;
    float si = sigf(iou[a]);
    const float4* row4 = (const float4*)hmp + (size_t)a * 20 + q;
    float4 v[5];
#pragma unroll
    for (int j = 0; j < 5; ++j) v[j] = row4[j * 4];
    float best = -1.0f;
    int bc = 0;
#pragma unroll
    for (int j = 0; j < 5; ++j) {
        int cb = j * 16 + q * 4;
        float f;
        f = sqrtf(sigf(v[j].x) * si); if (f > best) { best = f; bc = cb; }
        f = sqrtf(sigf(v[j].y) * si); if (f > best) { best = f; bc = cb + 1; }
        f = sqrtf(sigf(v[j].z) * si); if (f > best) { best = f; bc = cb + 2; }
        f = sqrtf(sigf(v[j].w) * si); if (f > best) { best = f; bc = cb + 3; }
    }
#pragma unroll
    for (int off = 1; off <= 2; off <<= 1) {
        float of = __shfl_xor(best, off);
        int   oc = __shfl_xor(bc, off);
        if (of > best || (of == best && oc < bc)) { best = of; bc = oc; }
    }
    if (q == 0) {
        scores[a] = best;
        labels[a] = (uint32_t)bc;
    }
}

// K1b: histogram with per-block LDS privatization. 64 blocks x 1024 thr,
// each block counts 1600 anchors, flushes only nonzero bins (<=64 colliders/bin).
__global__ __launch_bounds__(1024) void k_hist(const float* __restrict__ scores,
                                               uint32_t* __restrict__ hist) {
    __shared__ uint32_t lh[NBINS];
    for (int i = threadIdx.x; i < NBINS; i += 1024) lh[i] = 0u;
    __syncthreads();
    int base = blockIdx.x * 1600;
    for (int k = threadIdx.x; k < 1600; k += 1024) {
        uint32_t bin = __float_as_uint(scores[base + k]) >> 16;
        atomicAdd(&lh[bin], 1u);
    }
    __syncthreads();
    for (int i = threadIdx.x; i < NBINS; i += 1024) {
        uint32_t c = lh[i];
        if (c) atomicAdd(&hist[i], c);
    }
}

// K2: find 16-bit cutoff bin (largest B with count(bin >= B) >= 1000)
__global__ __launch_bounds__(1024) void k_cutoff(const uint32_t* __restrict__ hist,
                                                 uint32_t* __restrict__ meta) {
    __shared__ uint32_t part[1024];
    int t = threadIdx.x;
    uint32_t s = 0;
#pragma unroll
    for (int b = 0; b < 16; ++b) s += hist[t * 16 + b];
    part[t] = s;
    __syncthreads();
    for (int off = 1; off < 1024; off <<= 1) {
        uint32_t v = part[t] + ((t + off < 1024) ? part[t + off] : 0u);
        __syncthreads();
        part[t] = v;
        __syncthreads();
    }
    uint32_t inc   = part[t];
    uint32_t above = (t < 1023) ? part[t + 1] : 0u;
    if (above < K_TOP && inc >= K_TOP) {
        uint32_t loc[16];
#pragma unroll
        for (int b = 0; b < 16; ++b) loc[b] = hist[t * 16 + b];
        uint32_t cnt = above;
        for (int b = 15; b >= 0; --b) {
            cnt += loc[b];
            if (cnt >= K_TOP) { meta[0] = (uint32_t)(t * 16 + b); break; }
        }
    }
}

// K3: collect candidate keys (score_bits<<32 | ~index)
__global__ __launch_bounds__(256) void k_collect(const float* __restrict__ scores,
                                                 uint32_t* __restrict__ meta,
                                                 uint64_t* __restrict__ keys) {
    int i = blockIdx.x * 256 + threadIdx.x;
    if (i >= N_ANCH) return;
    uint32_t bits = __float_as_uint(scores[i]);
    if ((bits >> 16) >= meta[0]) {
        uint32_t pos = atomicAdd(&meta[2], 1u);
        if (pos < 4096)
            keys[pos] = ((uint64_t)bits << 32) | (uint64_t)(0xFFFFFFFFu - (uint32_t)i);
    }
}

// K4: brute-force exact ranking (keys unique) + gather/decode epilogue.
__global__ __launch_bounds__(64) void k_rank(const uint64_t* __restrict__ keys,
                                             const uint32_t* __restrict__ meta,
                                             const uint32_t* __restrict__ labels,
                                             const float* __restrict__ reg,
                                             float* __restrict__ out,
                                             float* __restrict__ boxes,
                                             uint32_t* __restrict__ lab1k) {
    __shared__ uint64_t sk[4096];
    int lane = threadIdx.x;
    uint32_t M = meta[2];
    if (M > 4096u) M = 4096u;
    if ((uint32_t)(blockIdx.x * 64) >= M) return;
    for (uint32_t i = lane; i < M; i += 64) sk[i] = keys[i];
    __syncthreads();
    int c = blockIdx.x * 64 + lane;
    if ((uint32_t)c >= M) return;
    uint64_t mykey = sk[c];
    uint32_t rank = 0;
    uint32_t i = 0;
    for (; i + 8 <= M; i += 8) {
#pragma unroll
        for (int u = 0; u < 8; ++u) rank += (sk[i + u] > mykey) ? 1u : 0u;
    }
    for (; i < M; ++i) rank += (sk[i] > mykey) ? 1u : 0u;
    if (rank >= K_TOP) return;
    int t = (int)rank;
    uint32_t sbits = (uint32_t)(mykey >> 32);
    uint32_t idx   = 0xFFFFFFFFu - (uint32_t)(mykey & 0xFFFFFFFFull);
    float score = __uint_as_float(sbits);
    uint32_t lab = labels[idx];
    out[t]         = score;
    out[K_TOP + t] = (float)lab;
    lab1k[t]       = lab;
    float ax = (float)(idx % FMP);
    float ay = (float)(idx / FMP);
    float4 rr = ((const float4*)reg)[idx];
    float e0 = expf(fminf(rr.x, SC_CLAMP));
    float e1 = expf(fminf(rr.y, SC_CLAMP));
    float e2 = expf(fminf(rr.z, SC_CLAMP));
    float e3 = expf(fminf(rr.w, SC_CLAMP));
    float x1 = fminf(fmaxf((ax - e0) * 4.0f / IMGF, 0.0f), 1.0f);
    float y1 = fminf(fmaxf((ay - e1) * 4.0f / IMGF, 0.0f), 1.0f);
    float x2 = fminf(fmaxf((ax + e2) * 4.0f / IMGF, 0.0f), 1.0f);
    float y2 = fminf(fmaxf((ay + e3) * 4.0f / IMGF, 0.0f), 1.0f);
    out[2 * K_TOP + t * 4 + 0] = x1;
    out[2 * K_TOP + t * 4 + 1] = y1;
    out[2 * K_TOP + t * 4 + 2] = x2;
    out[2 * K_TOP + t * 4 + 3] = y2;
    boxes[t * 4 + 0] = x1;
    boxes[t * 4 + 1] = y1;
    boxes[t * 4 + 2] = x2;
    boxes[t * 4 + 3] = y2;
}

// K5: suppress bitmask rows (only j > i bits). 1000 blocks x 256 thr;
// wave v of block i computes words v, v+4, v+8, v+12 of row i.
__global__ __launch_bounds__(256) void k_mask(const float* __restrict__ boxes,
                                              const uint32_t* __restrict__ lab1k,
                                              uint64_t* __restrict__ mask) {
    int i = blockIdx.x;
    int lane = threadIdx.x & 63;
    int wv = threadIdx.x >> 6;
    float4 bi = ((const float4*)boxes)[i];
    uint32_t li = lab1k[i];
    float areai = (bi.z - bi.x) * (bi.w - bi.y);
#pragma unroll
    for (int w0 = 0; w0 < 4; ++w0) {
        int w = wv + w0 * 4;
        int j = w * 64 + lane;
        bool sup = false;
        if (j < K_TOP && j > i) {
            float4 bj = ((const float4*)boxes)[j];
            float areaj = (bj.z - bj.x) * (bj.w - bj.y);
            float xx1 = fmaxf(bi.x, bj.x);
            float yy1 = fmaxf(bi.y, bj.y);
            float xx2 = fminf(bi.z, bj.z);
            float yy2 = fminf(bi.w, bj.w);
            float ww = fmaxf(1e-10f, xx2 - xx1);
            float hh = fmaxf(1e-10f, yy2 - yy1);
            float inter = ww * hh;
            float iouv = inter / (areai + areaj - inter + 1e-10f);
            sup = (iouv > NMS_T) && (li == lab1k[j]);
        }
        unsigned long long m = __ballot(sup);
        if (lane == 0) mask[(size_t)i * 16 + w] = (uint64_t)m;
    }
}

// K6: greedy scan, one wave. Rows prefetched 16 at a time into alternating
// register buffers (fully unrolled). Chunk word D kept wave-uniform; the
// row's word w comes from __shfl(cv[r], w) (off the serial chain).
__global__ __launch_bounds__(64) void k_nms(const uint64_t* __restrict__ mask,
                                            float* __restrict__ out) {
    int lane = threadIdx.x;
    uint64_t remv = 0ull;
    uint64_t A[16], B[16];
#pragma unroll
    for (int r = 0; r < 16; ++r)
        A[r] = (lane < 16) ? mask[(size_t)r * 16 + lane] : 0ull;
    uint64_t D = 0ull;
#pragma unroll
    for (int G = 0; G < 63; ++G) {           // 63 groups of 16 rows cover 1000
        uint64_t (&cv)[16] = (G & 1) ? B : A;
        uint64_t (&nv)[16] = (G & 1) ? A : B;
        if (G + 1 < 63) {
#pragma unroll
            for (int r = 0; r < 16; ++r) {
                int i = (G + 1) * 16 + r;
                nv[r] = (lane < 16 && i < K_TOP) ? mask[(size_t)i * 16 + lane] : 0ull;
            }
        }
        int w = (G * 16) >> 6;
        if ((G & 3) == 0) D = __shfl(remv, w);   // re-sync at chunk start
#pragma unroll
        for (int r = 0; r < 16; ++r) {
            int i = G * 16 + r;
            if (i >= K_TOP) break;
            int b = i & 63;
            uint64_t miw = __shfl(cv[r], w);
            uint64_t sel = ((D >> b) & 1ull) ? 0ull : ~0ull;
            D    |= miw & sel;
            remv |= cv[r] & sel;
        }
    }
#pragma unroll
    for (int g = 0; g < 16; ++g) {
        uint64_t rg = __shfl(remv, g);
        int j = g * 64 + lane;
        if (j < K_TOP) out[6 * K_TOP + j] = ((rg >> lane) & 1ull) ? 0.0f : 1.0f;
    }
}

extern "C" void kernel_launch(void* const* d_in, const int* in_sizes, int n_in,
                              void* d_out, int out_size, void* d_ws, size_t ws_size,
                              hipStream_t stream) {
    const float* hmp = (const float*)d_in[0];
    const float* reg = (const float*)d_in[1];
    const float* iou = (const float*)d_in[2];
    float* out = (float*)d_out;
    char* ws = (char*)d_ws;

    float*    scores = (float*)(ws + OFF_SCORES);
    uint32_t* labels = (uint32_t*)(ws + OFF_LABELS);
    uint32_t* hist   = (uint32_t*)(ws + OFF_HIST);
    uint32_t* meta   = (uint32_t*)(ws + OFF_META);
    uint64_t* keys   = (uint64_t*)(ws + OFF_KEYS);
    float*    boxes  = (float*)(ws + OFF_BOXES);
    uint32_t* lab1k  = (uint32_t*)(ws + OFF_LAB1K);
    uint64_t* mask   = (uint64_t*)(ws + OFF_MASK);

    k_zero<<<dim3((NBINS + 64 + 255) / 256), dim3(256), 0, stream>>>(hist);
    k_scores<<<dim3(N_ANCH * 4 / 256), dim3(256), 0, stream>>>(hmp, iou, scores, labels);
    k_hist<<<dim3(64), dim3(1024), 0, stream>>>(scores, hist);
    k_cutoff<<<dim3(1), dim3(1024), 0, stream>>>(hist, meta);
    k_collect<<<dim3((N_ANCH + 255) / 256), dim3(256), 0, stream>>>(scores, meta, keys);
    k_rank<<<dim3(64), dim3(64), 0, stream>>>(keys, meta, labels, reg, out, boxes, lab1k);
    k_mask<<<dim3(K_TOP), dim3(256), 0, stream>>>(boxes, lab1k, mask);
    k_nms<<<dim3(1), dim3(64), 0, stream>>>(mask, out);
}

// Round 4
// 195.597 us; speedup vs baseline: 2.2275x; 2.2275x over previous
//
#include <hip/hip_runtime.h>
#include <stdint.h>

#define N_ANCH 102400
#define FMP 320
#define NUM_CLASSES 80
#define K_TOP 1000
#define NMS_T 0.6f
#define SC_CLAMP 6.907755278982137f
#define IMGF 1280.0f
#define NBINS 16384   // scores in (0,1) => float bits>>16 < 0x4000

// ---- workspace layout (bytes) ----
#define OFF_SCORES   0u          // f32[102400]
#define OFF_LABELS   409600u     // u32[102400]
#define OFF_HIST     819200u     // u32[16384]
#define OFF_META     884736u     // u32[64]  [0]=cutoff bin, [2]=candidate counter
#define OFF_KEYS     884992u     // u64[4096]
#define OFF_BOXES    917760u     // f32[4000] (16B aligned)
#define OFF_LAB1K    933760u     // u32[1000]
#define OFF_MASK     937760u     // u64[16000]

__device__ __forceinline__ float sigf(float x) {
    return 1.0f / (1.0f + expf(-x));
}

// K0: zero hist (16384) + meta (64) — contiguous
__global__ __launch_bounds__(256) void k_zero(uint32_t* hist) {
    int i = blockIdx.x * 256 + threadIdx.x;
    if (i < NBINS + 64) hist[i] = 0u;
}

// K1: fused score + argmax. 4 threads per anchor, 5 float4 loads per thread.
// NO global atomics (hot-bin serialization cost 120us in R2).
__global__ __launch_bounds__(256) void k_scores(const float* __restrict__ hmp,
                                                const float* __restrict__ iou,
                                                float* __restrict__ scores,
                                                uint32_t* __restrict__ labels) {
    int gid = blockIdx.x * 256 + threadIdx.x;
    int a = gid >> 2;
    int q = gid & 3;
    float si = sigf(iou[a]);
    const float4* row4 = (const float4*)hmp + (size_t)a * 20 + q;
    float4 v[5];
#pragma unroll
    for (int j = 0; j < 5; ++j) v[j] = row4[j * 4];
    float best = -1.0f;
    int bc = 0;
#pragma unroll
    for (int j = 0; j < 5; ++j) {
        int cb = j * 16 + q * 4;
        float f;
        f = sqrtf(sigf(v[j].x) * si); if (f > best) { best = f; bc = cb; }
        f = sqrtf(sigf(v[j].y) * si); if (f > best) { best = f; bc = cb + 1; }
        f = sqrtf(sigf(v[j].z) * si); if (f > best) { best = f; bc = cb + 2; }
        f = sqrtf(sigf(v[j].w) * si); if (f > best) { best = f; bc = cb + 3; }
    }
#pragma unroll
    for (int off = 1; off <= 2; off <<= 1) {
        float of = __shfl_xor(best, off);
        int   oc = __shfl_xor(bc, off);
        if (of > best || (of == best && oc < bc)) { best = of; bc = oc; }
    }
    if (q == 0) {
        scores[a] = best;
        labels[a] = (uint32_t)bc;
    }
}

// K1b: histogram with per-block LDS privatization.
__global__ __launch_bounds__(1024) void k_hist(const float* __restrict__ scores,
                                               uint32_t* __restrict__ hist) {
    __shared__ uint32_t lh[NBINS];
    for (int i = threadIdx.x; i < NBINS; i += 1024) lh[i] = 0u;
    __syncthreads();
    int base = blockIdx.x * 1600;
    for (int k = threadIdx.x; k < 1600; k += 1024) {
        uint32_t bin = __float_as_uint(scores[base + k]) >> 16;
        atomicAdd(&lh[bin], 1u);
    }
    __syncthreads();
    for (int i = threadIdx.x; i < NBINS; i += 1024) {
        uint32_t c = lh[i];
        if (c) atomicAdd(&hist[i], c);
    }
}

// K2: find 16-bit cutoff bin (largest B with count(bin >= B) >= 1000)
__global__ __launch_bounds__(1024) void k_cutoff(const uint32_t* __restrict__ hist,
                                                 uint32_t* __restrict__ meta) {
    __shared__ uint32_t part[1024];
    int t = threadIdx.x;
    uint32_t s = 0;
#pragma unroll
    for (int b = 0; b < 16; ++b) s += hist[t * 16 + b];
    part[t] = s;
    __syncthreads();
    for (int off = 1; off < 1024; off <<= 1) {
        uint32_t v = part[t] + ((t + off < 1024) ? part[t + off] : 0u);
        __syncthreads();
        part[t] = v;
        __syncthreads();
    }
    uint32_t inc   = part[t];
    uint32_t above = (t < 1023) ? part[t + 1] : 0u;
    if (above < K_TOP && inc >= K_TOP) {
        uint32_t loc[16];
#pragma unroll
        for (int b = 0; b < 16; ++b) loc[b] = hist[t * 16 + b];
        uint32_t cnt = above;
        for (int b = 15; b >= 0; --b) {
            cnt += loc[b];
            if (cnt >= K_TOP) { meta[0] = (uint32_t)(t * 16 + b); break; }
        }
    }
}

// K3: collect candidate keys (score_bits<<32 | ~index)
__global__ __launch_bounds__(256) void k_collect(const float* __restrict__ scores,
                                                 uint32_t* __restrict__ meta,
                                                 uint64_t* __restrict__ keys) {
    int i = blockIdx.x * 256 + threadIdx.x;
    if (i >= N_ANCH) return;
    uint32_t bits = __float_as_uint(scores[i]);
    if ((bits >> 16) >= meta[0]) {
        uint32_t pos = atomicAdd(&meta[2], 1u);
        if (pos < 4096)
            keys[pos] = ((uint64_t)bits << 32) | (uint64_t)(0xFFFFFFFFu - (uint32_t)i);
    }
}

// K4: brute-force exact ranking (keys unique) + gather/decode epilogue.
__global__ __launch_bounds__(64) void k_rank(const uint64_t* __restrict__ keys,
                                             const uint32_t* __restrict__ meta,
                                             const uint32_t* __restrict__ labels,
                                             const float* __restrict__ reg,
                                             float* __restrict__ out,
                                             float* __restrict__ boxes,
                                             uint32_t* __restrict__ lab1k) {
    __shared__ uint64_t sk[4096];
    int lane = threadIdx.x;
    uint32_t M = meta[2];
    if (M > 4096u) M = 4096u;
    if ((uint32_t)(blockIdx.x * 64) >= M) return;
    for (uint32_t i = lane; i < M; i += 64) sk[i] = keys[i];
    __syncthreads();
    int c = blockIdx.x * 64 + lane;
    if ((uint32_t)c >= M) return;
    uint64_t mykey = sk[c];
    uint32_t rank = 0;
    uint32_t i = 0;
    for (; i + 8 <= M; i += 8) {
#pragma unroll
        for (int u = 0; u < 8; ++u) rank += (sk[i + u] > mykey) ? 1u : 0u;
    }
    for (; i < M; ++i) rank += (sk[i] > mykey) ? 1u : 0u;
    if (rank >= K_TOP) return;
    int t = (int)rank;
    uint32_t sbits = (uint32_t)(mykey >> 32);
    uint32_t idx   = 0xFFFFFFFFu - (uint32_t)(mykey & 0xFFFFFFFFull);
    float score = __uint_as_float(sbits);
    uint32_t lab = labels[idx];
    out[t]         = score;
    out[K_TOP + t] = (float)lab;
    lab1k[t]       = lab;
    float ax = (float)(idx % FMP);
    float ay = (float)(idx / FMP);
    float4 rr = ((const float4*)reg)[idx];
    float e0 = expf(fminf(rr.x, SC_CLAMP));
    float e1 = expf(fminf(rr.y, SC_CLAMP));
    float e2 = expf(fminf(rr.z, SC_CLAMP));
    float e3 = expf(fminf(rr.w, SC_CLAMP));
    float x1 = fminf(fmaxf((ax - e0) * 4.0f / IMGF, 0.0f), 1.0f);
    float y1 = fminf(fmaxf((ay - e1) * 4.0f / IMGF, 0.0f), 1.0f);
    float x2 = fminf(fmaxf((ax + e2) * 4.0f / IMGF, 0.0f), 1.0f);
    float y2 = fminf(fmaxf((ay + e3) * 4.0f / IMGF, 0.0f), 1.0f);
    out[2 * K_TOP + t * 4 + 0] = x1;
    out[2 * K_TOP + t * 4 + 1] = y1;
    out[2 * K_TOP + t * 4 + 2] = x2;
    out[2 * K_TOP + t * 4 + 3] = y2;
    boxes[t * 4 + 0] = x1;
    boxes[t * 4 + 1] = y1;
    boxes[t * 4 + 2] = x2;
    boxes[t * 4 + 3] = y2;
}

// K5: suppress bitmask rows (only j > i bits). 1000 blocks x 256 thr.
__global__ __launch_bounds__(256) void k_mask(const float* __restrict__ boxes,
                                              const uint32_t* __restrict__ lab1k,
                                              uint64_t* __restrict__ mask) {
    int i = blockIdx.x;
    int lane = threadIdx.x & 63;
    int wv = threadIdx.x >> 6;
    float4 bi = ((const float4*)boxes)[i];
    uint32_t li = lab1k[i];
    float areai = (bi.z - bi.x) * (bi.w - bi.y);
#pragma unroll
    for (int w0 = 0; w0 < 4; ++w0) {
        int w = wv + w0 * 4;
        int j = w * 64 + lane;
        bool sup = false;
        if (j < K_TOP && j > i) {
            float4 bj = ((const float4*)boxes)[j];
            float areaj = (bj.z - bj.x) * (bj.w - bj.y);
            float xx1 = fmaxf(bi.x, bj.x);
            float yy1 = fmaxf(bi.y, bj.y);
            float xx2 = fminf(bi.z, bj.z);
            float yy2 = fminf(bi.w, bj.w);
            float ww = fmaxf(1e-10f, xx2 - xx1);
            float hh = fmaxf(1e-10f, yy2 - yy1);
            float inter = ww * hh;
            float iouv = inter / (areai + areaj - inter + 1e-10f);
            sup = (iouv > NMS_T) && (li == lab1k[j]);
        }
        unsigned long long m = __ballot(sup);
        if (lane == 0) mask[(size_t)i * 16 + w] = (uint64_t)m;
    }
}

// K6: greedy scan, one wave. Statically ping-ponged register pipeline:
// outer iter g2 handles the 64 rows of word g2; A holds rows [64*g2, +32),
// B rows [64*g2+32, +32). No reference-swap, no dynamic indexing -> stays
// in VGPRs (R3's version spilled to scratch: VGPR_Count=12, 313us).
// Decision chain is scalar: miw via readlane (off-chain), sel/D scalar ops.
__global__ __launch_bounds__(64) void k_nms(const uint64_t* __restrict__ mask,
                                            float* __restrict__ out) {
    int lane = threadIdx.x;
    bool act = lane < 16;
    uint64_t remv = 0ull;
    uint64_t A[32], B[32];
#pragma unroll
    for (int r = 0; r < 32; ++r)
        A[r] = act ? mask[(size_t)r * 16 + lane] : 0ull;   // rows 0..31
    for (int g2 = 0; g2 < 16; ++g2) {
        // prefetch odd half (rows 64*g2+32 .. +63) -> B
#pragma unroll
        for (int r = 0; r < 32; ++r) {
            int i = g2 * 64 + 32 + r;
            int ri = (i < K_TOP) ? i : 0;
            B[r] = (act && i < K_TOP) ? mask[(size_t)ri * 16 + lane] : 0ull;
        }
        uint64_t D = ((uint64_t)__builtin_amdgcn_readlane((uint32_t)(remv >> 32), g2) << 32)
                   | __builtin_amdgcn_readlane((uint32_t)remv, g2);
        // process even half: bits 0..31 of word g2
#pragma unroll
        for (int r = 0; r < 32; ++r) {
            uint64_t miw = ((uint64_t)__builtin_amdgcn_readlane((uint32_t)(A[r] >> 32), g2) << 32)
                         | __builtin_amdgcn_readlane((uint32_t)A[r], g2);
            uint64_t sel = ((D >> r) & 1ull) ? 0ull : ~0ull;
            D    |= miw & sel;
            remv |= A[r] & sel;
        }
        // prefetch next even half (rows 64*(g2+1) .. +31) -> A
        if (g2 < 15) {
#pragma unroll
            for (int r = 0; r < 32; ++r) {
                int i = (g2 + 1) * 64 + r;
                A[r] = act ? mask[(size_t)i * 16 + lane] : 0ull;   // i <= 991 < K_TOP
            }
        }
        // process odd half: bits 32..63 of word g2
#pragma unroll
        for (int r = 0; r < 32; ++r) {
            uint64_t miw = ((uint64_t)__builtin_amdgcn_readlane((uint32_t)(B[r] >> 32), g2) << 32)
                         | __builtin_amdgcn_readlane((uint32_t)B[r], g2);
            uint64_t sel = ((D >> (32 + r)) & 1ull) ? 0ull : ~0ull;
            D    |= miw & sel;
            remv |= B[r] & sel;
        }
    }
#pragma unroll
    for (int g = 0; g < 16; ++g) {
        uint64_t rg = __shfl(remv, g);
        int j = g * 64 + lane;
        if (j < K_TOP) out[6 * K_TOP + j] = ((rg >> lane) & 1ull) ? 0.0f : 1.0f;
    }
}

extern "C" void kernel_launch(void* const* d_in, const int* in_sizes, int n_in,
                              void* d_out, int out_size, void* d_ws, size_t ws_size,
                              hipStream_t stream) {
    const float* hmp = (const float*)d_in[0];
    const float* reg = (const float*)d_in[1];
    const float* iou = (const float*)d_in[2];
    float* out = (float*)d_out;
    char* ws = (char*)d_ws;

    float*    scores = (float*)(ws + OFF_SCORES);
    uint32_t* labels = (uint32_t*)(ws + OFF_LABELS);
    uint32_t* hist   = (uint32_t*)(ws + OFF_HIST);
    uint32_t* meta   = (uint32_t*)(ws + OFF_META);
    uint64_t* keys   = (uint64_t*)(ws + OFF_KEYS);
    float*    boxes  = (float*)(ws + OFF_BOXES);
    uint32_t* lab1k  = (uint32_t*)(ws + OFF_LAB1K);
    uint64_t* mask   = (uint64_t*)(ws + OFF_MASK);

    k_zero<<<dim3((NBINS + 64 + 255) / 256), dim3(256), 0, stream>>>(hist);
    k_scores<<<dim3(N_ANCH * 4 / 256), dim3(256), 0, stream>>>(hmp, iou, scores, labels);
    k_hist<<<dim3(64), dim3(1024), 0, stream>>>(scores, hist);
    k_cutoff<<<dim3(1), dim3(1024), 0, stream>>>(hist, meta);
    k_collect<<<dim3((N_ANCH + 255) / 256), dim3(256), 0, stream>>>(scores, meta, keys);
    k_rank<<<dim3(64), dim3(64), 0, stream>>>(keys, meta, labels, reg, out, boxes, lab1k);
    k_mask<<<dim3(K_TOP), dim3(256), 0, stream>>>(boxes, lab1k, mask);
    k_nms<<<dim3(1), dim3(64), 0, stream>>>(mask, out);
}